// Round 9
// baseline (147.626 us; speedup 1.0000x reference)
//
#include <hip/hip_runtime.h>
#include <math.h>

#define N1 50000
#define N2 50000
#define NE 640000
#define D 128
#define AD 64
#define EPSN 1e-8f

#define SCAN_BLK 256
#define NSB ((N1 + SCAN_BLK - 1) / SCAN_BLK)  // 196
#define NORM_BLKS (N2 / 8)                    // 6250

typedef _Float16 half2_t __attribute__((ext_vector_type(2)));

__device__ __forceinline__ half2_t pkh(float a, float b) {
    return __builtin_bit_cast(half2_t, __builtin_amdgcn_cvt_pkrtz(a, b));
}
__device__ __forceinline__ unsigned h2u(half2_t h) { return __builtin_bit_cast(unsigned, h); }
__device__ __forceinline__ half2_t u2h(unsigned u) { return __builtin_bit_cast(half2_t, u); }

// ---- preprocessing: Wg transpose | X2 inv-norms + f16 copy | zero cnt ---

__global__ __launch_bounds__(256) void pre_kernel(const float* __restrict__ Wg,
                                                  float2* __restrict__ WgT2g,
                                                  const float* __restrict__ X2,
                                                  float* __restrict__ inv2,
                                                  uint2* __restrict__ X2h,
                                                  int* __restrict__ cnt) {
    int bid = blockIdx.x;
    if (bid < 16) {
        // WgT2g[k*64+j2] = (Wg[2j2][k], Wg[2j2+1][k]); Wg is [D][AD] row-major
        int t = bid * 256 + threadIdx.x;
        int k = t >> 6, j2 = t & 63;
        WgT2g[t] = make_float2(Wg[(size_t)(2 * j2) * AD + k],
                               Wg[(size_t)(2 * j2 + 1) * AD + k]);
    } else if (bid < 16 + NORM_BLKS) {
        int row = (bid - 16) * 8 + (threadIdx.x >> 5);  // < 50000 always
        int l32 = threadIdx.x & 31;
        float4 v = ((const float4*)(X2 + (size_t)row * D))[l32];
        // f16 copy: row = 128 f16 = 32 uint2 per row
        X2h[(size_t)row * 32 + l32] = make_uint2(h2u(pkh(v.x, v.y)), h2u(pkh(v.z, v.w)));
        float s = v.x * v.x + v.y * v.y + v.z * v.z + v.w * v.w;
        #pragma unroll
        for (int off = 16; off > 0; off >>= 1) s += __shfl_xor(s, off);
        if (l32 == 0) inv2[row] = 1.0f / fmaxf(sqrtf(s), EPSN);
    } else {
        int idx = (bid - 16 - NORM_BLKS) * 256 + threadIdx.x;
        if (idx < N1) cnt[idx] = 0;
    }
}

// ---- CSR build ----------------------------------------------------------

__global__ void hist_kernel(const int* __restrict__ src, int* __restrict__ cnt) {
    int e = blockIdx.x * blockDim.x + threadIdx.x;
    if (e < NE) atomicAdd(&cnt[src[e]], 1);
}

// phase 1: per-block (256 elems) exclusive scan + block totals
__global__ __launch_bounds__(256) void scan1_kernel(const int* __restrict__ cnt,
                                                    int* __restrict__ rowptr,
                                                    int* __restrict__ bsum) {
    __shared__ int wsum[4];
    int tid = threadIdx.x, lane = tid & 63, wid = tid >> 6;
    int idx = blockIdx.x * SCAN_BLK + tid;
    int v = (idx < N1) ? cnt[idx] : 0;
    int x = v;  // inclusive wave scan
    #pragma unroll
    for (int off = 1; off < 64; off <<= 1) {
        int y = __shfl_up(x, off);
        if (lane >= off) x += y;
    }
    if (lane == 63) wsum[wid] = x;
    __syncthreads();
    if (tid == 0) {
        int s = 0;
        #pragma unroll
        for (int w = 0; w < 4; ++w) { int t = wsum[w]; wsum[w] = s; s += t; }
        bsum[blockIdx.x] = s;
    }
    __syncthreads();
    if (idx < N1) rowptr[idx] = x - v + wsum[wid];  // block-local exclusive
}

// phase 2+3 fused: each block computes its own bsum prefix (<=196 ints),
// adds it, writes rowptr + cursor. Last block also writes rowptr[N1].
__global__ __launch_bounds__(256) void scan23_kernel(int* __restrict__ rowptr,
                                                     const int* __restrict__ bsum,
                                                     int* __restrict__ cursor) {
    __shared__ int wsum[4];
    __shared__ int pref_s;
    int tid = threadIdx.x, lane = tid & 63, wid = tid >> 6;
    int bid = blockIdx.x;
    int v = (tid < bid) ? bsum[tid] : 0;
    #pragma unroll
    for (int off = 32; off > 0; off >>= 1) v += __shfl_xor(v, off);
    if (lane == 0) wsum[wid] = v;
    __syncthreads();
    if (tid == 0) {
        int p = wsum[0] + wsum[1] + wsum[2] + wsum[3];
        pref_s = p;
        if (bid == NSB - 1) rowptr[N1] = p + bsum[NSB - 1];
    }
    __syncthreads();
    int prefix = pref_s;
    int idx = bid * SCAN_BLK + tid;
    if (idx < N1) {
        int r = rowptr[idx] + prefix;
        rowptr[idx] = r;
        cursor[idx] = r;
    }
}

// scatter dst indices into CSR order
__global__ void fill_kernel(const int* __restrict__ src, const int* __restrict__ dst,
                            int* __restrict__ cursor, int* __restrict__ csr_dst) {
    int e = blockIdx.x * blockDim.x + threadIdx.x;
    if (e < NE) {
        int p = atomicAdd(&cursor[src[e]], 1);
        csr_dst[p] = dst[e];
    }
}

// ---- gates: sigmoid(Xn @ Wg^T) -> f16 ws buffer -------------------------
// Register-tiled; node index wave-uniform (readfirstlane) -> Xn loads go
// through the scalar path. Writes gates packed f16 (no out RMW).
__global__ __launch_bounds__(256) void gate_kernel(const float* __restrict__ Xn,
                                                   const float2* __restrict__ WgT2g,
                                                   unsigned* __restrict__ gates) {
    __shared__ float2 WgT2[AD * 64];  // 32 KB
    for (int t = threadIdx.x; t < AD * 64; t += 256) WgT2[t] = WgT2g[t];
    __syncthreads();

    int j2 = threadIdx.x & 63;  // lane: output columns (2*j2, 2*j2+1)
    int slot = __builtin_amdgcn_readfirstlane(threadIdx.x >> 6);
    int base = blockIdx.x * 64 + slot * 16;  // 782 blocks

    #pragma unroll
    for (int g = 0; g < 4; ++g) {
        int n0 = base + g * 4;
        if (n0 >= N1) break;  // wave-uniform tail guard
        const float* x0 = Xn + (size_t)n0 * AD;
        const float* x1 = x0 + AD;
        const float* x2 = x0 + 2 * AD;
        const float* x3 = x0 + 3 * AD;
        float a00 = 0.f, a01 = 0.f, a10 = 0.f, a11 = 0.f;
        float a20 = 0.f, a21 = 0.f, a30 = 0.f, a31 = 0.f;
        #pragma unroll
        for (int k = 0; k < AD; ++k) {
            float2 w = WgT2[k * 64 + j2];
            float v0 = x0[k], v1 = x1[k], v2 = x2[k], v3 = x3[k];
            a00 += v0 * w.x; a01 += v0 * w.y;
            a10 += v1 * w.x; a11 += v1 * w.y;
            a20 += v2 * w.x; a21 += v2 * w.y;
            a30 += v3 * w.x; a31 += v3 * w.y;
        }
        float g00 = 1.0f / (1.0f + __expf(-a00));
        float g01 = 1.0f / (1.0f + __expf(-a01));
        float g10 = 1.0f / (1.0f + __expf(-a10));
        float g11 = 1.0f / (1.0f + __expf(-a11));
        float g20 = 1.0f / (1.0f + __expf(-a20));
        float g21 = 1.0f / (1.0f + __expf(-a21));
        float g30 = 1.0f / (1.0f + __expf(-a30));
        float g31 = 1.0f / (1.0f + __expf(-a31));
        gates[(size_t)n0 * 64 + j2]       = h2u(pkh(g00, g01));
        gates[(size_t)(n0 + 1) * 64 + j2] = h2u(pkh(g10, g11));
        gates[(size_t)(n0 + 2) * 64 + j2] = h2u(pkh(g20, g21));
        gates[(size_t)(n0 + 3) * 64 + j2] = h2u(pkh(g30, g31));
    }
}

// ---- fused per-node pass: cosine sim + softmax + agg + gate apply -------
// One wave per source node; 4 edges in flight (16 lanes/edge, 8 f16
// cols/lane). Dot via v_dot2_f32_f16. cos in [-1,1] -> softmax needs no
// max subtraction (exp(sim) in [0.37,2.72]; shift-invariant == reference).
__global__ __launch_bounds__(256) void node_kernel(const float* __restrict__ X1,
                                                   const uint4* __restrict__ X2h,
                                                   const int* __restrict__ rowptr,
                                                   const int* __restrict__ csr_dst,
                                                   const float* __restrict__ inv2,
                                                   const unsigned* __restrict__ gates,
                                                   float* __restrict__ out) {
    int i = blockIdx.x * 4 + (threadIdx.x >> 6);  // 12500*4 == N1, no tail
    int lane = threadIdx.x & 63;
    int q = lane >> 4, l16 = lane & 15;  // quarter q owns edge eb+q

    // lane covers columns 8*l16 .. 8*l16+7 (all 4 quarters replicate the row)
    const float4* p1 = (const float4*)(X1 + (size_t)i * D);
    float4 a0 = p1[2 * l16], a1 = p1[2 * l16 + 1];
    float s = a0.x * a0.x + a0.y * a0.y + a0.z * a0.z + a0.w * a0.w
            + a1.x * a1.x + a1.y * a1.y + a1.z * a1.z + a1.w * a1.w;
    #pragma unroll
    for (int off = 8; off > 0; off >>= 1) s += __shfl_xor(s, off);
    float inv1 = 1.0f / fmaxf(sqrtf(s), EPSN);

    // pack this lane's X1 slice to half2 x4 (once per node)
    half2_t ah0 = pkh(a0.x, a0.y);
    half2_t ah1 = pkh(a0.z, a0.w);
    half2_t ah2 = pkh(a1.x, a1.y);
    half2_t ah3 = pkh(a1.z, a1.w);

    int e0 = rowptr[i], e1 = rowptr[i + 1];
    float ssum = 0.0f;
    float4 acc0 = make_float4(0.f, 0.f, 0.f, 0.f);
    float4 acc1 = make_float4(0.f, 0.f, 0.f, 0.f);

    // 1-deep prefetch; this quarter's first edge (row = 16 x uint4 of f16)
    uint4 braw = make_uint4(0u, 0u, 0u, 0u);
    float iv = 0.f;
    {
        int e = e0 + q;
        if (e < e1) { int dn = csr_dst[e]; braw = X2h[(size_t)dn * 16 + l16]; iv = inv2[dn]; }
    }

    for (int eb = e0; eb < e1; eb += 4) {
        uint4 bc = braw; float ivc = iv;
        int en = eb + 4 + q;
        if (en < e1) { int dn = csr_dst[en]; braw = X2h[(size_t)dn * 16 + l16]; iv = inv2[dn]; }
        half2_t h0 = u2h(bc.x), h1 = u2h(bc.y), h2 = u2h(bc.z), h3 = u2h(bc.w);
        float pd = __builtin_amdgcn_fdot2(ah0, h0,
                   __builtin_amdgcn_fdot2(ah1, h1,
                   __builtin_amdgcn_fdot2(ah2, h2,
                   __builtin_amdgcn_fdot2(ah3, h3, 0.f, false), false), false), false);
        #pragma unroll
        for (int off = 8; off > 0; off >>= 1) pd += __shfl_xor(pd, off);
        if (eb + q < e1) {
            float ex = __expf(pd * inv1 * ivc);
            ssum += ex;
            acc0.x += ex * (float)h0.x; acc0.y += ex * (float)h0.y;
            acc0.z += ex * (float)h1.x; acc0.w += ex * (float)h1.y;
            acc1.x += ex * (float)h2.x; acc1.y += ex * (float)h2.y;
            acc1.z += ex * (float)h3.x; acc1.w += ex * (float)h3.y;
        }
    }

    // sum the 4 quarter states (no max bookkeeping needed)
    #pragma unroll
    for (int off = 16; off <= 32; off <<= 1) {
        ssum   += __shfl_xor(ssum, off);
        acc0.x += __shfl_xor(acc0.x, off); acc0.y += __shfl_xor(acc0.y, off);
        acc0.z += __shfl_xor(acc0.z, off); acc0.w += __shfl_xor(acc0.w, off);
        acc1.x += __shfl_xor(acc1.x, off); acc1.y += __shfl_xor(acc1.y, off);
        acc1.z += __shfl_xor(acc1.z, off); acc1.w += __shfl_xor(acc1.w, off);
    }
    float invs = (ssum > 0.f) ? (1.0f / ssum) : 0.f;  // empty segment -> 0
    if (lane < 16) {
        uint4 gu = ((const uint4*)(gates + (size_t)i * 64))[l16];
        half2_t g0 = u2h(gu.x), g1 = u2h(gu.y), g2 = u2h(gu.z), g3 = u2h(gu.w);
        float4* orow = (float4*)(out + (size_t)i * D);
        orow[2 * l16]     = make_float4(acc0.x * invs * (float)g0.x,
                                        acc0.y * invs * (float)g0.y,
                                        acc0.z * invs * (float)g1.x,
                                        acc0.w * invs * (float)g1.y);
        orow[2 * l16 + 1] = make_float4(acc1.x * invs * (float)g2.x,
                                        acc1.y * invs * (float)g2.y,
                                        acc1.z * invs * (float)g3.x,
                                        acc1.w * invs * (float)g3.y);
    }
}

// ---- launch -------------------------------------------------------------

extern "C" void kernel_launch(void* const* d_in, const int* in_sizes, int n_in,
                              void* d_out, int out_size, void* d_ws, size_t ws_size,
                              hipStream_t stream) {
    const float* X1 = (const float*)d_in[0];
    const float* X2 = (const float*)d_in[1];
    const float* Xn = (const float*)d_in[2];
    const int*   ci = (const int*)d_in[3];
    const float* Wg = (const float*)d_in[4];
    float* out = (float*)d_out;

    const int* src = ci;
    const int* dst = ci + NE;

    char* ws = (char*)d_ws;
    uint2*    X2h    = (uint2*)ws;    ws += (size_t)N2 * D * 2;          // 12.8 MB
    unsigned* gates  = (unsigned*)ws; ws += (size_t)N1 * 64 * 4;         // 12.8 MB
    float2*   WgT2g  = (float2*)ws;   ws += AD * 64 * sizeof(float2);
    int*      cnt    = (int*)ws;      ws += N1 * sizeof(int);
    int*      rowptr = (int*)ws;      ws += (N1 + 1) * sizeof(int);
    int*      cursor = (int*)ws;      ws += N1 * sizeof(int);
    int*      csr_dst= (int*)ws;      ws += NE * sizeof(int);
    float*    inv2   = (float*)ws;    ws += N2 * sizeof(float);
    int*      bsum   = (int*)ws;      ws += NSB * sizeof(int);

    pre_kernel<<<16 + NORM_BLKS + NSB, 256, 0, stream>>>(Wg, WgT2g, X2, inv2, X2h, cnt);
    gate_kernel<<<(N1 + 63) / 64, 256, 0, stream>>>(Xn, WgT2g, gates);
    hist_kernel<<<(NE + 255) / 256, 256, 0, stream>>>(src, cnt);
    scan1_kernel<<<NSB, SCAN_BLK, 0, stream>>>(cnt, rowptr, bsum);
    scan23_kernel<<<NSB, SCAN_BLK, 0, stream>>>(rowptr, bsum, cursor);
    fill_kernel<<<(NE + 255) / 256, 256, 0, stream>>>(src, dst, cursor, csr_dst);
    node_kernel<<<N1 / 4, 256, 0, stream>>>(X1, (const uint4*)X2h, rowptr, csr_dst,
                                            inv2, gates, out);
}